// Round 6
// baseline (27035.336 us; speedup 1.0000x reference)
//
#include <hip/hip_runtime.h>
#include <math.h>

#define NB 8192
enum { ACT_NONE = 0, ACT_RELU = 1, ACT_TANH = 2 };

// ---------------------------------------------------------------------------
// fp64 tiled GEMM: C[rows,N](f64) = act(A[rows,K] @ W[K,N](f32) + bias(f32)
// + addsrc(f64)).  A is f32 (exact upcast) or f64.  BM=BN=64, BK=16,
// 256 threads, 4x4 micro-tile. rows%64==0, K%16==0, N arbitrary.
// ---------------------------------------------------------------------------
template<typename TA, int ACT, bool HB, bool HA>
__global__ __launch_bounds__(256)
void dgemm_k(const TA* __restrict__ A, int lda,
             const float* __restrict__ W, int ldw,
             const float* __restrict__ bias,
             const double* __restrict__ addsrc, int ldadd,
             double* __restrict__ C, int ldc, int N, int K)
{
    __shared__ double As[16][64];
    __shared__ double Bs[16][64];
    const int tid = threadIdx.x;
    const int tx = tid & 15, ty = tid >> 4;
    const size_t m0 = (size_t)blockIdx.y * 64;
    const int n0 = blockIdx.x * 64;
    const int ar = tid >> 2, akc = (tid & 3) * 4;
    const int bkr = tid >> 4, bcc = (tid & 15) * 4;

    double acc[4][4] = {};

    for (int kt = 0; kt < K; kt += 16) {
        const TA* ap = A + (m0 + ar) * (size_t)lda + kt + akc;
        if constexpr (sizeof(TA) == 4) {
            float4 v = *(const float4*)ap;
            As[akc + 0][ar] = (double)v.x; As[akc + 1][ar] = (double)v.y;
            As[akc + 2][ar] = (double)v.z; As[akc + 3][ar] = (double)v.w;
        } else {
            double2 v0 = *(const double2*)ap;
            double2 v1 = *(const double2*)(ap + 2);
            As[akc + 0][ar] = v0.x; As[akc + 1][ar] = v0.y;
            As[akc + 2][ar] = v1.x; As[akc + 3][ar] = v1.y;
        }
        const float* wp = W + (size_t)(kt + bkr) * ldw + n0 + bcc;
#pragma unroll
        for (int e = 0; e < 4; e++) {
            int gc = n0 + bcc + e;
            Bs[bkr][bcc + e] = (gc < N) ? (double)wp[e] : 0.0;
        }
        __syncthreads();
#pragma unroll
        for (int k = 0; k < 16; k++) {
            double a[4], b[4];
#pragma unroll
            for (int i = 0; i < 4; i++) a[i] = As[k][ty * 4 + i];
#pragma unroll
            for (int j = 0; j < 4; j++) b[j] = Bs[k][tx * 4 + j];
#pragma unroll
            for (int i = 0; i < 4; i++)
#pragma unroll
                for (int j = 0; j < 4; j++)
                    acc[i][j] = fma(a[i], b[j], acc[i][j]);
        }
        __syncthreads();
    }

#pragma unroll
    for (int i = 0; i < 4; i++) {
        size_t gr = m0 + ty * 4 + i;
#pragma unroll
        for (int j = 0; j < 4; j++) {
            int gc = n0 + tx * 4 + j;
            if (gc < N) {
                double v = acc[i][j];
                if (HB) v += (double)bias[gc];
                if (HA) v += addsrc[gr * (size_t)ldadd + gc];
                if (ACT == ACT_RELU) v = v > 0.0 ? v : 0.0;
                if (ACT == ACT_TANH) v = tanh(v);
                C[gr * (size_t)ldc + gc] = v;
            }
        }
    }
}

// msg = relu(W[idx] + b) in fp64
__global__ void msg_build_d(const float* __restrict__ Wt, const float* __restrict__ bias,
                            const int* __restrict__ idx, int istride, int ioff,
                            double* __restrict__ out, int ldo, int ooff)
{
    int b = blockIdx.x;
    int j = threadIdx.x;   // 256
    int id = idx[(size_t)b * istride + ioff];
    double v = (double)Wt[(size_t)id * 256 + j] + (double)bias[j];
    out[(size_t)b * ldo + ooff + j] = v > 0.0 ? v : 0.0;
}

// fp64 softmax; DECISIONS on f32-rounded p with stable lower-index ties.
// sout stores the f32-rounded probability (as float).
__global__ __launch_bounds__(256)
void softmax_topk_q(const double* __restrict__ logits, int ldl, int N, int k,
                    float* __restrict__ sout, int sstride, int soff,
                    int* __restrict__ iout, int istride, int ioff)
{
    int wave = threadIdx.x >> 6;
    int lane = threadIdx.x & 63;
    int b = blockIdx.x * 4 + wave;
    const double* row = logits + (size_t)b * ldl;

    double v[4];
#pragma unroll
    for (int j = 0; j < 4; j++) {
        int c = lane + j * 64;
        v[j] = (c < N) ? row[c] : -INFINITY;
    }
    double mx = fmax(fmax(v[0], v[1]), fmax(v[2], v[3]));
    for (int o = 32; o; o >>= 1) mx = fmax(mx, __shfl_xor(mx, o, 64));

    double e[4];
    double se = 0.0;
#pragma unroll
    for (int j = 0; j < 4; j++) {
        int c = lane + j * 64;
        if (c < N) { e[j] = exp(v[j] - mx); se += e[j]; }
        else e[j] = 0.0;
    }
    for (int o = 32; o; o >>= 1) se += __shfl_xor(se, o, 64);

    // f32-quantized decision values (refs compare f32 probabilities)
    float p[4];
#pragma unroll
    for (int j = 0; j < 4; j++) {
        int c = lane + j * 64;
        p[j] = (c < N) ? (float)(e[j] / se) : -1.f;
    }

    for (int kk = 0; kk < k; kk++) {
        float bv = -1.f; int bi = 1 << 20;
#pragma unroll
        for (int j = 0; j < 4; j++) {        // j ascending = index ascending:
            if (p[j] > bv) { bv = p[j]; bi = lane + j * 64; }   // strict > = stable
        }
        for (int o = 32; o; o >>= 1) {
            float ov = __shfl_xor(bv, o, 64);
            int   oi = __shfl_xor(bi, o, 64);
            if (ov > bv || (ov == bv && oi < bi)) { bv = ov; bi = oi; }  // tie -> lower idx
        }
        if (lane == 0) {
            sout[(size_t)b * sstride + soff + kk] = bv;
            iout[(size_t)b * istride + ioff + kk] = bi;
        }
#pragma unroll
        for (int j = 0; j < 4; j++) if (lane + j * 64 == bi) p[j] = -1.f;
    }
}

// joint scores: f32 left-assoc product chain of f32 probs (exactly as refs),
// stable descending argsort (strict >, earliest index on ties).
__global__ void finalize_q(const float* __restrict__ s0, const float* __restrict__ s1,
                           const float* __restrict__ s2, const float* __restrict__ s3,
                           const float* __restrict__ s4,
                           const int* __restrict__ i0, const int* __restrict__ i1,
                           const int* __restrict__ i2, const int* __restrict__ i3,
                           const int* __restrict__ i4,
                           int* __restrict__ out)
{
    int b = blockIdx.x * 256 + threadIdx.x;
    float sc[15];
    float a0 = s0[b];
    for (int t = 0; t < 15; t++) {
        int a = t / 5;
        float v = a0 * s1[b * 3 + a];
        v = v * s2[b * 3 + a];
        v = v * s3[b * 15 + t];
        v = v * s4[b * 15 + t];
        sc[t] = v;
    }
    bool used[15] = {false};
    for (int r = 0; r < 15; r++) {
        int best = -1; float bv = -INFINITY;
        for (int t = 0; t < 15; t++)
            if (!used[t] && sc[t] > bv) { bv = sc[t]; best = t; }  // stable
        used[best] = true;
        int a = best / 5;
        int* o = out + (size_t)b * 75 + r * 5;
        o[0] = i0[b];
        o[1] = i1[b * 3 + a];
        o[2] = i2[b * 3 + a];
        o[3] = i3[b * 15 + best];
        o[4] = i4[b * 15 + best];
    }
}

// ---------------- host-side dispatch ----------------
static void dgemm(hipStream_t st, int a_is_f32, const void* A, int lda,
                  const float* W, int ldw, const float* bias,
                  const double* add, int ldadd, double* C, int ldc,
                  int rows, int N, int K, int act)
{
    dim3 grid((N + 63) / 64, rows / 64);
#define LK(TA, AC, HBv, HAv) hipLaunchKernelGGL((dgemm_k<TA, AC, HBv, HAv>), grid, dim3(256), 0, st, \
        (const TA*)A, lda, W, ldw, bias, add, ldadd, C, ldc, N, K)
#define ACTS(TA, HBv, HAv) do { if (act == 0) LK(TA, 0, HBv, HAv); \
                                else if (act == 1) LK(TA, 1, HBv, HAv); \
                                else LK(TA, 2, HBv, HAv); } while (0)
#define BDISP(TA) do { if (bias) { if (add) ACTS(TA, true, true); else ACTS(TA, true, false); } \
                       else      { if (add) ACTS(TA, false, true); else ACTS(TA, false, false); } } while (0)
    if (a_is_f32) BDISP(float); else BDISP(double);
#undef BDISP
#undef ACTS
#undef LK
}

extern "C" void kernel_launch(void* const* d_in, const int* in_sizes, int n_in,
                              void* d_out, int out_size, void* d_ws, size_t ws_size,
                              hipStream_t stream)
{
    (void)in_sizes; (void)n_in; (void)out_size;
    const float* feat = (const float*)d_in[0];
    const float* Wc  = (const float*)d_in[1];
    const float* bc  = (const float*)d_in[2];
    const float* Ws1 = (const float*)d_in[3];
    const float* bs1 = (const float*)d_in[4];
    const float* Ws2 = (const float*)d_in[5];
    const float* bs2 = (const float*)d_in[6];
    const float* Wr  = (const float*)d_in[7];
    const float* br  = (const float*)d_in[8];
    auto Wh1 = [&](int i) { return (const float*)d_in[9 + 6 * i]; };
    auto bh1 = [&](int i) { return (const float*)d_in[10 + 6 * i]; };
    auto Wh2 = [&](int i) { return (const float*)d_in[11 + 6 * i]; };
    auto bh2 = [&](int i) { return (const float*)d_in[12 + 6 * i]; };
    auto Wo  = [&](int i) { return (const float*)d_in[13 + 6 * i]; };
    auto bo  = [&](int i) { return (const float*)d_in[14 + 6 * i]; };
    const int outs[5] = {54, 87, 87, 235, 235};

    // per-row: 6400 work doubles + 37 score floats + 37 ints = 51,496 B
    const size_t perRow = 6400ull * 8 + 37ull * 4 + 37ull * 4;
    int R = NB;
    while (R > 256 && (size_t)R * perRow > ws_size) R >>= 1;

    double* ws = (double*)d_ws;
    size_t off = 0;
    auto alloc = [&](size_t n) { double* p = ws + off; off += n; return p; };
    double* msg0 = alloc((size_t)R * 256);
    double* xm0  = alloc((size_t)R * 512);
    double* xm1  = alloc((size_t)R * 512);
    double* xm2  = alloc((size_t)R * 512);
    double* xms[3] = {xm0, xm1, xm2};
    double* bufC = alloc((size_t)R * 1024);
    double* base = alloc((size_t)R * 1024);
    double* h1   = alloc((size_t)R * 1024);
    double* h2   = alloc((size_t)R * 1024);
    double* lg   = alloc((size_t)R * 256);
    double* m3   = alloc((size_t)R * 256);
    float* fbase = (float*)(ws + off);
    float* s0 = fbase;            float* s1 = fbase + R;
    float* s2 = s1 + 3 * R;       float* s3 = s2 + 3 * R;
    float* s4 = s3 + 15 * R;
    int* ibase = (int*)(s4 + 15 * R);
    int* i0 = ibase;              int* i1 = ibase + R;
    int* i2 = i1 + 3 * R;         int* i3 = i2 + 3 * R;
    int* i4 = i3 + 15 * R;

    for (int r0 = 0; r0 < NB; r0 += R) {
        const float* fC = feat + (size_t)r0 * 1024;
        dim3 tkg(R / 4);

        // ---- stage 0 (K=1024) ----
        dgemm(stream, 1, fC, 1024, Wh1(0), 1024, bh1(0), nullptr, 0, h1, 1024, R, 1024, 1024, ACT_RELU);
        dgemm(stream, 0, h1, 1024, Wh2(0), 1024, bh2(0), nullptr, 0, h2, 1024, R, 1024, 1024, ACT_TANH);
        dgemm(stream, 0, h2, 1024, Wo(0), outs[0], bo(0), nullptr, 0, lg, outs[0], R, outs[0], 1024, ACT_NONE);
        hipLaunchKernelGGL(softmax_topk_q, tkg, dim3(256), 0, stream, lg, outs[0], outs[0], 1, s0, 1, 0, i0, 1, 0);
        hipLaunchKernelGGL(msg_build_d, dim3(R), dim3(256), 0, stream, Wc, bc, i0, 1, 0, msg0, 256, 0);

        // ---- stage 1 (K=1280) ----
        dgemm(stream, 1, fC, 1024, Wh1(1), 1024, nullptr, nullptr, 0, bufC, 1024, R, 1024, 1024, ACT_NONE);
        dgemm(stream, 0, msg0, 256, Wh1(1) + (size_t)1024 * 1024, 1024, bh1(1), bufC, 1024, h1, 1024, R, 1024, 256, ACT_RELU);
        dgemm(stream, 0, h1, 1024, Wh2(1), 1024, bh2(1), nullptr, 0, h2, 1024, R, 1024, 1024, ACT_TANH);
        dgemm(stream, 0, h2, 1024, Wo(1), outs[1], bo(1), nullptr, 0, lg, outs[1], R, outs[1], 1024, ACT_NONE);
        hipLaunchKernelGGL(softmax_topk_q, tkg, dim3(256), 0, stream, lg, outs[1], outs[1], 3, s1, 3, 0, i1, 3, 0);
        for (int a = 0; a < 3; a++)
            hipLaunchKernelGGL(msg_build_d, dim3(R), dim3(256), 0, stream, Ws1, bs1, i1, 3, a, xms[a], 512, 0);

        // ---- stage 2 (K=1536) ----
        dgemm(stream, 1, fC, 1024, Wh1(2), 1024, nullptr, nullptr, 0, bufC, 1024, R, 1024, 1024, ACT_NONE);
        dgemm(stream, 0, msg0, 256, Wh1(2) + (size_t)1024 * 1024, 1024, nullptr, bufC, 1024, bufC, 1024, R, 1024, 256, ACT_NONE);
        for (int a = 0; a < 3; a++) {
            dgemm(stream, 0, xms[a], 512, Wh1(2) + (size_t)1280 * 1024, 1024, bh1(2), bufC, 1024, h1, 1024, R, 1024, 256, ACT_RELU);
            dgemm(stream, 0, h1, 1024, Wh2(2), 1024, bh2(2), nullptr, 0, h2, 1024, R, 1024, 1024, ACT_TANH);
            dgemm(stream, 0, h2, 1024, Wo(2), outs[2], bo(2), nullptr, 0, lg, outs[2], R, outs[2], 1024, ACT_NONE);
            hipLaunchKernelGGL(softmax_topk_q, tkg, dim3(256), 0, stream, lg, outs[2], outs[2], 1, s2, 3, a, i2, 3, a);
        }
        for (int a = 0; a < 3; a++)
            hipLaunchKernelGGL(msg_build_d, dim3(R), dim3(256), 0, stream, Ws2, bs2, i2, 3, a, xms[a], 512, 256);

        // ---- stage 3 (K=1792) ----
        dgemm(stream, 1, fC, 1024, Wh1(3), 1024, nullptr, nullptr, 0, bufC, 1024, R, 1024, 1024, ACT_NONE);
        dgemm(stream, 0, msg0, 256, Wh1(3) + (size_t)1024 * 1024, 1024, nullptr, bufC, 1024, bufC, 1024, R, 1024, 256, ACT_NONE);
        for (int a = 0; a < 3; a++) {
            dgemm(stream, 0, xms[a], 512, Wh1(3) + (size_t)1280 * 1024, 1024, bh1(3), bufC, 1024, h1, 1024, R, 1024, 512, ACT_RELU);
            dgemm(stream, 0, h1, 1024, Wh2(3), 1024, bh2(3), nullptr, 0, h2, 1024, R, 1024, 1024, ACT_TANH);
            dgemm(stream, 0, h2, 1024, Wo(3), outs[3], bo(3), nullptr, 0, lg, outs[3], R, outs[3], 1024, ACT_NONE);
            hipLaunchKernelGGL(softmax_topk_q, tkg, dim3(256), 0, stream, lg, outs[3], outs[3], 5, s3, 15, 5 * a, i3, 15, 5 * a);
        }

        // ---- stage 4 (K=2048) ----
        dgemm(stream, 1, fC, 1024, Wh1(4), 1024, nullptr, nullptr, 0, bufC, 1024, R, 1024, 1024, ACT_NONE);
        dgemm(stream, 0, msg0, 256, Wh1(4) + (size_t)1024 * 1024, 1024, nullptr, bufC, 1024, bufC, 1024, R, 1024, 256, ACT_NONE);
        for (int a = 0; a < 3; a++) {
            dgemm(stream, 0, xms[a], 512, Wh1(4) + (size_t)1280 * 1024, 1024, nullptr, bufC, 1024, base, 1024, R, 1024, 512, ACT_NONE);
            for (int c = 0; c < 5; c++) {
                int t = a * 5 + c;
                hipLaunchKernelGGL(msg_build_d, dim3(R), dim3(256), 0, stream, Wr, br, i3, 15, t, m3, 256, 0);
                dgemm(stream, 0, m3, 256, Wh1(4) + (size_t)1792 * 1024, 1024, bh1(4), base, 1024, h1, 1024, R, 1024, 256, ACT_RELU);
                dgemm(stream, 0, h1, 1024, Wh2(4), 1024, bh2(4), nullptr, 0, h2, 1024, R, 1024, 1024, ACT_TANH);
                dgemm(stream, 0, h2, 1024, Wo(4), outs[4], bo(4), nullptr, 0, lg, outs[4], R, outs[4], 1024, ACT_NONE);
                hipLaunchKernelGGL(softmax_topk_q, tkg, dim3(256), 0, stream, lg, outs[4], outs[4], 1, s4, 15, t, i4, 15, t);
            }
        }

        // ---- final join + stable descending argsort on f32 products ----
        hipLaunchKernelGGL(finalize_q, dim3(R / 256), dim3(256), 0, stream,
                           s0, s1, s2, s3, s4, i0, i1, i2, i3, i4, (int*)d_out + (size_t)r0 * 75);
    }
}